// Round 6
// baseline (602.435 us; speedup 1.0000x reference)
//
#include <hip/hip_runtime.h>
#include <hip/hip_bf16.h>

typedef __attribute__((ext_vector_type(8)))  short short8;   // 8 bf16
typedef __attribute__((ext_vector_type(8)))  int   int8v;    // 32 fp8
typedef __attribute__((ext_vector_type(4)))  float f32x4;
typedef __attribute__((ext_vector_type(16))) float f32x16;

#define K_DIM 1024
#define KT_N  32
#define M_TOK 2048
#define V_DIM 128000

// softcap s = 30*tanh(l/30);  exp(s-30) = exp2(C2/(t+1)) with t = exp2(l*C1)
#define CAP_C1 0.09617966939259757f
#define CAP_C2 -86.56170245333781f
// fp8 path: W pre-scaled by 32 -> raw logit = 32*l_true; fold into C1
#define CAP_C1S (0.09617966939259757f / 32.0f)

// workspace layout (bytes)
#define WS_ROWSUM 0
#define WS_SLABEL 8192
#define WS_XQ     16384
#define WS_XFB    (16384 + (2u << 20))
#define WS_WQ     (16384 + (2u << 20) + (4u << 20))
#define WS_REQ    ((size_t)WS_WQ + (size_t)V_DIM * K_DIM)

static __device__ __forceinline__ short f2bf(float f) {
    unsigned u = __float_as_uint(f);
    u += 0x7FFFu + ((u >> 16) & 1u);
    return (short)(u >> 16);
}
static __device__ __forceinline__ short8 pack8(float4 a, float4 b) {
    short8 r;
    r[0] = f2bf(a.x); r[1] = f2bf(a.y); r[2] = f2bf(a.z); r[3] = f2bf(a.w);
    r[4] = f2bf(b.x); r[5] = f2bf(b.y); r[6] = f2bf(b.z); r[7] = f2bf(b.w);
    return r;
}
static __device__ __forceinline__ void gload16(const void* g, void* lds) {
    __builtin_amdgcn_global_load_lds(
        (const __attribute__((address_space(1))) unsigned int*)g,
        (__attribute__((address_space(3))) unsigned int*)lds, 16, 0, 0);
}
static __device__ __forceinline__ int cvt4(float4 f, float mul) {
    int w = 0;
    w = __builtin_amdgcn_cvt_pk_fp8_f32(f.x * mul, f.y * mul, w, false);
    w = __builtin_amdgcn_cvt_pk_fp8_f32(f.z * mul, f.w * mul, w, true);
    return w;
}

// ---------------- f32 row-major -> fp8 e4m3 MFMA fragment stream ----------------
// stream int4 index: ((mtg32*16 + t)*2 + h)*64 + lane
// lane l of frag mtg32 holds row = mtg32*32 + (l&31), k = t*64 + (l>>5)*32 + h*16 + 0..15
__global__ __launch_bounds__(256) void convert_fp8_kernel(const float* __restrict__ src,
                                                          int4* __restrict__ dst, float mul) {
    int o  = blockIdx.x * 256 + threadIdx.x;
    int l  = o & 63;
    int ft = o >> 6;                      // mtg32*16 + t
    int row = (ft >> 4) * 32 + (l & 31);
    int k   = ((ft & 15) << 6) + ((l >> 5) << 5);
    const float4* s = (const float4*)(src + (size_t)row * K_DIM + k);
    float4 f0 = s[0], f1 = s[1], f2 = s[2], f3 = s[3];
    float4 f4 = s[4], f5 = s[5], f6 = s[6], f7 = s[7];
    dst[((size_t)ft * 2 + 0) * 64 + l] =
        make_int4(cvt4(f0, mul), cvt4(f1, mul), cvt4(f2, mul), cvt4(f3, mul));
    dst[((size_t)ft * 2 + 1) * 64 + l] =
        make_int4(cvt4(f4, mul), cvt4(f5, mul), cvt4(f6, mul), cvt4(f7, mul));
}

// ---------------- bf16 converter (fallback path only) ----------------
__global__ __launch_bounds__(256) void convert_x_kernel(const float* __restrict__ x,
                                                        short8* __restrict__ xf) {
    int o = blockIdx.x * 256 + threadIdx.x;
    int lane = o & 63;
    int frag = o >> 6;
    int kt = frag & (KT_N - 1);
    int mt = frag >> 5;
    int row = (mt << 4) | (lane & 15);
    int k   = (kt << 5) | ((lane >> 4) << 3);
    const float4* s = (const float4*)(x + (size_t)row * K_DIM + k);
    xf[o] = pack8(s[0], s[1]);
}

static __device__ __forceinline__ int8v ld_frag(const int4* buf, int f, int lane) {
    int4 lo = buf[(f * 2 + 0) * 64 + lane];
    int4 hi = buf[(f * 2 + 1) * 64 + lane];
    int8v r;
    r[0] = lo.x; r[1] = lo.y; r[2] = lo.z; r[3] = lo.w;
    r[4] = hi.x; r[5] = hi.y; r[6] = hi.z; r[7] = hi.w;
    return r;
}
static __device__ __forceinline__ float expterm(float lraw) {
    return exp2f(CAP_C2 * __builtin_amdgcn_rcpf(exp2f(lraw * CAP_C1S) + 1.0f));
}

// ---------------- MX-fp8 GEMM, 3-ring counted-vmcnt pipeline ----------------
// BM=256 vocab x BN=128 tok, BK=64, 16 K-steps. 8 waves (4 vocab x 2 tok),
// wave tile 64x64 = 2x2 frags of 32x32x64. LDS ring of 3 (72 KiB).
// Per step: s_waitcnt vmcnt(3) -> s_barrier -> issue stage(t+2) -> compute(t).
// Loads stay 2 steps in flight; vmcnt never drained to 0 in the main loop.
__global__ __launch_bounds__(512, 2) void gemm_sumexp_fp8_pipe(const int4* __restrict__ wq,
                                                               const int4* __restrict__ xq,
                                                               float* __restrict__ rowsum) {
    __shared__ int4 As[3][1024];         // 8 chunks x 2 halves x 64 lanes, 16 KiB/buf
    __shared__ int4 Bs[3][512];          // 4 chunks x 2 halves x 64 lanes,  8 KiB/buf

    int bid = blockIdx.x;
    int wk  = (bid & 7) * 1000 + (bid >> 3);   // XCD swizzle, 8000 % 8 == 0
    int vt  = wk >> 4;                   // vocab tile 0..499 (256 rows)
    int tt  = wk & 15;                   // token tile 0..15  (128 tokens)

    const int tid  = threadIdx.x;
    const int lane = tid & 63;
    const int wv   = tid >> 6;           // wave 0..7
    const int wr   = wv >> 1;            // 0..3 vocab quadrant
    const int wc   = wv & 1;             // 0..1 token half

    // global fragment-stream bases (int4 units)
    const int4* ga = wq + (size_t)(vt * 8 + wv) * 2048 + lane;                 // A: wave wv stages mtg_l = wv
    const int4* gb = xq + (size_t)(tt * 4 + (wv >> 1)) * 2048 + (wv & 1) * 64 + lane; // B: chunk wv

#define STAGE(bt, t) do {                                             \
        gload16(ga + (size_t)(t) * 128,      &As[bt][(wv * 2 + 0) * 64]); \
        gload16(ga + (size_t)(t) * 128 + 64, &As[bt][(wv * 2 + 1) * 64]); \
        gload16(gb + (size_t)(t) * 128,      &Bs[bt][wv * 64]);           \
    } while (0)

    f32x16 acc[2][2] = {};

#define COMPUTE(bt) do {                                              \
        const int4* Ab = &As[bt][0];                                  \
        const int4* Bb = &Bs[bt][0];                                  \
        int8v a0 = ld_frag(Ab, 2 * wr + 0, lane);                     \
        int8v a1 = ld_frag(Ab, 2 * wr + 1, lane);                     \
        int8v b0 = ld_frag(Bb, 2 * wc + 0, lane);                     \
        int8v b1 = ld_frag(Bb, 2 * wc + 1, lane);                     \
        __builtin_amdgcn_s_setprio(1);                                \
        acc[0][0] = __builtin_amdgcn_mfma_scale_f32_32x32x64_f8f6f4(  \
            a0, b0, acc[0][0], 0, 0, 0, 0x7F7F7F7F, 0, 0x7F7F7F7F);   \
        acc[0][1] = __builtin_amdgcn_mfma_scale_f32_32x32x64_f8f6f4(  \
            a0, b1, acc[0][1], 0, 0, 0, 0x7F7F7F7F, 0, 0x7F7F7F7F);   \
        acc[1][0] = __builtin_amdgcn_mfma_scale_f32_32x32x64_f8f6f4(  \
            a1, b0, acc[1][0], 0, 0, 0, 0x7F7F7F7F, 0, 0x7F7F7F7F);   \
        acc[1][1] = __builtin_amdgcn_mfma_scale_f32_32x32x64_f8f6f4(  \
            a1, b1, acc[1][1], 0, 0, 0, 0x7F7F7F7F, 0, 0x7F7F7F7F);   \
        __builtin_amdgcn_s_setprio(0);                                \
    } while (0)

#define PHASE(bt_stage, ts, bt_comp) do {                             \
        asm volatile("s_waitcnt vmcnt(3)" ::: "memory");              \
        __builtin_amdgcn_s_barrier();                                 \
        asm volatile("" ::: "memory");                                \
        if ((ts) < 16) STAGE(bt_stage, ts);                           \
        COMPUTE(bt_comp);                                             \
    } while (0)

    // prologue: steps 0,1 in flight (6 outstanding loads per wave)
    STAGE(0, 0);
    STAGE(1, 1);

    for (int tb = 0; tb < 15; tb += 3) {
        PHASE(2, tb + 2, 0);             // step tb
        PHASE(0, tb + 3, 1);             // step tb+1
        PHASE(1, tb + 4, 2);             // step tb+2
    }
    // tail: step 15 (buf 0), all loads done
    asm volatile("s_waitcnt vmcnt(0)" ::: "memory");
    __builtin_amdgcn_s_barrier();
    asm volatile("" ::: "memory");
    COMPUTE(0);

#undef PHASE
#undef COMPUTE
#undef STAGE

    // epilogue: softcap+exp, reduce over this wave's 64 vocab rows, atomics per token
    #pragma unroll
    for (int j = 0; j < 2; ++j) {
        float e = 0.f;
        #pragma unroll
        for (int m = 0; m < 2; ++m) {
            #pragma unroll
            for (int r = 0; r < 16; ++r) e += expterm(acc[m][j][r]);
        }
        e += __shfl_xor(e, 32, 64);      // lanes l, l+32 hold same token col, other row half
        if (lane < 32) {
            atomicAdd(&rowsum[tt * 128 + (wc * 2 + j) * 32 + lane], e);
        }
    }
}

// ---------------- fallback GEMM (bf16, W f32 reg-staged) — used if ws too small ----------------
__global__ __launch_bounds__(256, 3) void gemm_sumexp_fb(const float* __restrict__ W,
                                                         const short8* __restrict__ xf,
                                                         float* __restrict__ rowsum) {
    __shared__ short8 As[2][512];
    __shared__ short8 Bs[2][512];
    int bid = blockIdx.x;
    int wk  = (bid & 7) * 2000 + (bid >> 3);
    int vt  = wk >> 4;
    int tt  = wk & 15;
    const int tid  = threadIdx.x;
    const int lane = tid & 63;
    const int wid  = tid >> 6;
    const int wr   = (wid >> 1) & 1;
    const int wc   = wid & 1;
    const int mt_s = tid >> 5;
    const int sl   = tid & 31;
    const float* arow_p = W + (size_t)(vt * 128 + mt_s * 16 + (sl & 15)) * K_DIM + ((sl >> 4) << 3);
    const int nt0 = wid << 1;
    const char* gb_base = (const char*)xf + ((((size_t)(tt * 8 + nt0)) * KT_N) * 64 + lane) * 16;
    {
        const float4* gaq = (const float4*)(arow_p + 0);
        float4 p0 = gaq[0], p1 = gaq[1], p2 = gaq[4], p3 = gaq[5];
        gload16(gb_base,         &Bs[0][nt0 * 64]);
        gload16(gb_base + 32768, &Bs[0][(nt0 + 1) * 64]);
        As[0][mt_s * 64 + sl]      = pack8(p0, p1);
        As[0][mt_s * 64 + sl + 32] = pack8(p2, p3);
    }
    __syncthreads();
    f32x4 acc[4][4] = {};
    int cur = 0;
    for (int t = 0; t < 32; ++t) {
        float4 q0, q1, q2, q3;
        if (t + 1 < 32) {
            const float4* gaq = (const float4*)(arow_p + (t + 1) * 32);
            q0 = gaq[0]; q1 = gaq[1]; q2 = gaq[4]; q3 = gaq[5];
            gload16(gb_base + (size_t)(t + 1) * 1024,         &Bs[cur ^ 1][nt0 * 64]);
            gload16(gb_base + (size_t)(t + 1) * 1024 + 32768, &Bs[cur ^ 1][(nt0 + 1) * 64]);
        }
        short8 af0 = As[cur][(wr * 4 + 0) * 64 + lane];
        short8 af1 = As[cur][(wr * 4 + 1) * 64 + lane];
        short8 af2 = As[cur][(wr * 4 + 2) * 64 + lane];
        short8 af3 = As[cur][(wr * 4 + 3) * 64 + lane];
        short8 bf0 = Bs[cur][(wc * 4 + 0) * 64 + lane];
        short8 bf1 = Bs[cur][(wc * 4 + 1) * 64 + lane];
        short8 bf2 = Bs[cur][(wc * 4 + 2) * 64 + lane];
        short8 bf3 = Bs[cur][(wc * 4 + 3) * 64 + lane];
        acc[0][0] = __builtin_amdgcn_mfma_f32_16x16x32_bf16(af0, bf0, acc[0][0], 0, 0, 0);
        acc[0][1] = __builtin_amdgcn_mfma_f32_16x16x32_bf16(af0, bf1, acc[0][1], 0, 0, 0);
        acc[0][2] = __builtin_amdgcn_mfma_f32_16x16x32_bf16(af0, bf2, acc[0][2], 0, 0, 0);
        acc[0][3] = __builtin_amdgcn_mfma_f32_16x16x32_bf16(af0, bf3, acc[0][3], 0, 0, 0);
        acc[1][0] = __builtin_amdgcn_mfma_f32_16x16x32_bf16(af1, bf0, acc[1][0], 0, 0, 0);
        acc[1][1] = __builtin_amdgcn_mfma_f32_16x16x32_bf16(af1, bf1, acc[1][1], 0, 0, 0);
        acc[1][2] = __builtin_amdgcn_mfma_f32_16x16x32_bf16(af1, bf2, acc[1][2], 0, 0, 0);
        acc[1][3] = __builtin_amdgcn_mfma_f32_16x16x32_bf16(af1, bf3, acc[1][3], 0, 0, 0);
        acc[2][0] = __builtin_amdgcn_mfma_f32_16x16x32_bf16(af2, bf0, acc[2][0], 0, 0, 0);
        acc[2][1] = __builtin_amdgcn_mfma_f32_16x16x32_bf16(af2, bf1, acc[2][1], 0, 0, 0);
        acc[2][2] = __builtin_amdgcn_mfma_f32_16x16x32_bf16(af2, bf2, acc[2][2], 0, 0, 0);
        acc[2][3] = __builtin_amdgcn_mfma_f32_16x16x32_bf16(af2, bf3, acc[2][3], 0, 0, 0);
        acc[3][0] = __builtin_amdgcn_mfma_f32_16x16x32_bf16(af3, bf0, acc[3][0], 0, 0, 0);
        acc[3][1] = __builtin_amdgcn_mfma_f32_16x16x32_bf16(af3, bf1, acc[3][1], 0, 0, 0);
        acc[3][2] = __builtin_amdgcn_mfma_f32_16x16x32_bf16(af3, bf2, acc[3][2], 0, 0, 0);
        acc[3][3] = __builtin_amdgcn_mfma_f32_16x16x32_bf16(af3, bf3, acc[3][3], 0, 0, 0);
        if (t + 1 < 32) {
            As[cur ^ 1][mt_s * 64 + sl]      = pack8(q0, q1);
            As[cur ^ 1][mt_s * 64 + sl + 32] = pack8(q2, q3);
        }
        __syncthreads();
        cur ^= 1;
    }
    float s0 = 0.f, s1 = 0.f, s2 = 0.f, s3 = 0.f;
    #pragma unroll
    for (int mi = 0; mi < 4; ++mi) {
        #pragma unroll
        for (int r = 0; r < 4; ++r) {
            float l0 = acc[mi][0][r], l1 = acc[mi][1][r];
            float l2 = acc[mi][2][r], l3 = acc[mi][3][r];
            s0 += exp2f(CAP_C2 * __builtin_amdgcn_rcpf(exp2f(l0 * CAP_C1) + 1.0f));
            s1 += exp2f(CAP_C2 * __builtin_amdgcn_rcpf(exp2f(l1 * CAP_C1) + 1.0f));
            s2 += exp2f(CAP_C2 * __builtin_amdgcn_rcpf(exp2f(l2 * CAP_C1) + 1.0f));
            s3 += exp2f(CAP_C2 * __builtin_amdgcn_rcpf(exp2f(l3 * CAP_C1) + 1.0f));
        }
    }
    s0 += __shfl_xor(s0, 16, 64); s0 += __shfl_xor(s0, 32, 64);
    s1 += __shfl_xor(s1, 16, 64); s1 += __shfl_xor(s1, 32, 64);
    s2 += __shfl_xor(s2, 16, 64); s2 += __shfl_xor(s2, 32, 64);
    s3 += __shfl_xor(s3, 16, 64); s3 += __shfl_xor(s3, 32, 64);
    if (lane < 16) {
        int tbase = tt * 128 + wc * 64 + lane;
        atomicAdd(&rowsum[tbase +  0], s0);
        atomicAdd(&rowsum[tbase + 16], s1);
        atomicAdd(&rowsum[tbase + 32], s2);
        atomicAdd(&rowsum[tbase + 48], s3);
    }
}

// ---------------- exact-f32 label logits ----------------
__global__ __launch_bounds__(256) void label_kernel(const float* __restrict__ x,
                                                    const float* __restrict__ W,
                                                    const int* __restrict__ target,
                                                    float* __restrict__ slabel) {
    int t    = blockIdx.x * 4 + (threadIdx.x >> 6);
    int lane = threadIdx.x & 63;
    int tg   = target[t];
    int lbl  = (tg == -100) ? 0 : tg;
    const float4* xr = (const float4*)(x + (size_t)t * K_DIM);
    const float4* wv = (const float4*)(W + (size_t)lbl * K_DIM);
    float sum = 0.0f;
    #pragma unroll
    for (int i = 0; i < 4; ++i) {
        float4 a = xr[lane + i * 64];
        float4 b = wv[lane + i * 64];
        sum += a.x * b.x + a.y * b.y + a.z * b.z + a.w * b.w;
    }
    #pragma unroll
    for (int off = 1; off < 64; off <<= 1) sum += __shfl_xor(sum, off, 64);
    if (lane == 0) {
        float t0 = exp2f(sum * CAP_C1);
        slabel[t] = 30.0f - 60.0f / (t0 + 1.0f);
    }
}

// ---------------- finalize ----------------
__global__ __launch_bounds__(256) void finalize_kernel(const float* __restrict__ rowsum,
                                                       const float* __restrict__ slabel,
                                                       const int* __restrict__ target,
                                                       float* __restrict__ out) {
    __shared__ double ssum[4];
    __shared__ int    scnt[4];
    int w    = threadIdx.x >> 6;
    int lane = threadIdx.x & 63;
    double acc = 0.0;
    int cnt = 0;
    #pragma unroll
    for (int j = 0; j < 8; ++j) {
        int t = w * 512 + j * 64 + lane;
        int tg = target[t];
        if (tg != -100) {
            float lse = 30.0f + logf(rowsum[t]);
            acc += (double)(slabel[t] - lse);
            cnt += 1;
        }
    }
    #pragma unroll
    for (int off = 1; off < 64; off <<= 1) {
        acc += __shfl_xor(acc, off, 64);
        cnt += __shfl_xor(cnt, off, 64);
    }
    if (lane == 0) { ssum[w] = acc; scnt[w] = cnt; }
    __syncthreads();
    if (threadIdx.x == 0) {
        double c0 = ssum[0] / (double)scnt[0];
        double c1 = ssum[1] / (double)scnt[1];
        double r0 = ssum[2] / (double)scnt[2];
        double r1 = ssum[3] / (double)scnt[3];
        out[0] = (float)(-0.1 * 0.5 * ((c0 - r0) + (c1 - r1)));
    }
}

extern "C" void kernel_launch(void* const* d_in, const int* in_sizes, int n_in,
                              void* d_out, int out_size, void* d_ws, size_t ws_size,
                              hipStream_t stream) {
    const float* x      = (const float*)d_in[0];
    const float* W      = (const float*)d_in[1];
    const int*   target = (const int*)d_in[2];
    float*       out    = (float*)d_out;

    char*   ws     = (char*)d_ws;
    float*  rowsum = (float*)(ws + WS_ROWSUM);
    float*  slabel = (float*)(ws + WS_SLABEL);

    hipMemsetAsync(rowsum, 0, M_TOK * sizeof(float), stream);

    if (ws_size >= WS_REQ) {
        int4* xq = (int4*)(ws + WS_XQ);
        int4* wq = (int4*)(ws + WS_WQ);
        convert_fp8_kernel<<<256, 256, 0, stream>>>(x, xq, 1.0f);
        convert_fp8_kernel<<<16000, 256, 0, stream>>>(W, wq, 32.0f);
        gemm_sumexp_fp8_pipe<<<8000, 512, 0, stream>>>(wq, xq, rowsum);
    } else {
        short8* xf = (short8*)(ws + WS_XFB);
        convert_x_kernel<<<M_TOK * (K_DIM / 8) / 256, 256, 0, stream>>>(x, xf);
        gemm_sumexp_fb<<<16000, 256, 0, stream>>>(W, xf, rowsum);
    }

    label_kernel<<<M_TOK / 4, 256, 0, stream>>>(x, W, target, slabel);
    finalize_kernel<<<1, 256, 0, stream>>>(rowsum, slabel, target, out);
}

// Round 7
// 474.217 us; speedup vs baseline: 1.2704x; 1.2704x over previous
//
#include <hip/hip_runtime.h>
#include <hip/hip_bf16.h>

typedef __attribute__((ext_vector_type(8)))  short short8;   // 8 bf16
typedef __attribute__((ext_vector_type(8)))  int   int8v;    // 32 fp8
typedef __attribute__((ext_vector_type(4)))  float f32x4;
typedef __attribute__((ext_vector_type(16))) float f32x16;

#define K_DIM 1024
#define KT_N  32
#define M_TOK 2048
#define V_DIM 128000

// softcap s = 30*tanh(l/30);  exp(s-30) = exp2(C2/(t+1)) with t = exp2(l*C1)
#define CAP_C1 0.09617966939259757f
#define CAP_C2 -86.56170245333781f
// fp8 path: W pre-scaled by 32 -> raw logit = 32*l_true; fold into C1
#define CAP_C1S (0.09617966939259757f / 32.0f)

// workspace layout (bytes)
#define WS_ROWSUM 0
#define WS_SLABEL 8192
#define WS_XQ     16384
#define WS_XFB    (16384 + (2u << 20))
#define WS_WQ     (16384 + (2u << 20) + (4u << 20))
#define WS_REQ    ((size_t)WS_WQ + (size_t)V_DIM * K_DIM)

static __device__ __forceinline__ short f2bf(float f) {
    unsigned u = __float_as_uint(f);
    u += 0x7FFFu + ((u >> 16) & 1u);
    return (short)(u >> 16);
}
static __device__ __forceinline__ short8 pack8(float4 a, float4 b) {
    short8 r;
    r[0] = f2bf(a.x); r[1] = f2bf(a.y); r[2] = f2bf(a.z); r[3] = f2bf(a.w);
    r[4] = f2bf(b.x); r[5] = f2bf(b.y); r[6] = f2bf(b.z); r[7] = f2bf(b.w);
    return r;
}
static __device__ __forceinline__ void gload16(const void* g, void* lds) {
    __builtin_amdgcn_global_load_lds(
        (const __attribute__((address_space(1))) unsigned int*)g,
        (__attribute__((address_space(3))) unsigned int*)lds, 16, 0, 0);
}
static __device__ __forceinline__ int cvt4(float4 f, float mul) {
    int w = 0;
    w = __builtin_amdgcn_cvt_pk_fp8_f32(f.x * mul, f.y * mul, w, false);
    w = __builtin_amdgcn_cvt_pk_fp8_f32(f.z * mul, f.w * mul, w, true);
    return w;
}

// ---------------- f32 row-major -> fp8 e4m3 MFMA fragment stream ----------------
// stream int4 index: ((mtg32*16 + t)*2 + h)*64 + lane
// lane l of frag mtg32 holds row = mtg32*32 + (l&31), k = t*64 + (l>>5)*32 + h*16 + 0..15
__global__ __launch_bounds__(256) void convert_fp8_kernel(const float* __restrict__ src,
                                                          int4* __restrict__ dst, float mul) {
    int o  = blockIdx.x * 256 + threadIdx.x;
    int l  = o & 63;
    int ft = o >> 6;                      // mtg32*16 + t
    int row = (ft >> 4) * 32 + (l & 31);
    int k   = ((ft & 15) << 6) + ((l >> 5) << 5);
    const float4* s = (const float4*)(src + (size_t)row * K_DIM + k);
    float4 f0 = s[0], f1 = s[1], f2 = s[2], f3 = s[3];
    float4 f4 = s[4], f5 = s[5], f6 = s[6], f7 = s[7];
    dst[((size_t)ft * 2 + 0) * 64 + l] =
        make_int4(cvt4(f0, mul), cvt4(f1, mul), cvt4(f2, mul), cvt4(f3, mul));
    dst[((size_t)ft * 2 + 1) * 64 + l] =
        make_int4(cvt4(f4, mul), cvt4(f5, mul), cvt4(f6, mul), cvt4(f7, mul));
}

// ---------------- bf16 converter (fallback path only) ----------------
__global__ __launch_bounds__(256) void convert_x_kernel(const float* __restrict__ x,
                                                        short8* __restrict__ xf) {
    int o = blockIdx.x * 256 + threadIdx.x;
    int lane = o & 63;
    int frag = o >> 6;
    int kt = frag & (KT_N - 1);
    int mt = frag >> 5;
    int row = (mt << 4) | (lane & 15);
    int k   = (kt << 5) | ((lane >> 4) << 3);
    const float4* s = (const float4*)(x + (size_t)row * K_DIM + k);
    xf[o] = pack8(s[0], s[1]);
}

static __device__ __forceinline__ int8v ld_frag(const int4* buf, int f, int lane) {
    int4 lo = buf[(f * 2 + 0) * 64 + lane];
    int4 hi = buf[(f * 2 + 1) * 64 + lane];
    int8v r;
    r[0] = lo.x; r[1] = lo.y; r[2] = lo.z; r[3] = lo.w;
    r[4] = hi.x; r[5] = hi.y; r[6] = hi.z; r[7] = hi.w;
    return r;
}
static __device__ __forceinline__ float expterm(float lraw) {
    return exp2f(CAP_C2 * __builtin_amdgcn_rcpf(exp2f(lraw * CAP_C1S) + 1.0f));
}

// ---------------- MX-fp8 GEMM, 3-ring counted-vmcnt, 128x128 tile ----------------
// BM=128 vocab x BN=128 tok, BK=64, 16 K-steps. 4 waves (2 vocab x 2 tok),
// wave tile 64x64 = 2x2 frags of 32x32x64. LDS ring of 3 (48 KiB -> 3 blocks/CU).
// Per step: s_waitcnt vmcnt(4) -> s_barrier -> issue stage(t+2) -> compute(t).
// Loads stay ~2 steps in flight; vmcnt never drained to 0 in the main loop.
__global__ __launch_bounds__(256, 3) void gemm_sumexp_fp8_ring(const int4* __restrict__ wq,
                                                               const int4* __restrict__ xq,
                                                               float* __restrict__ rowsum) {
    __shared__ int4 As[3][512];          // 4 frags x 2 halves x 64 lanes, 8 KiB/buf
    __shared__ int4 Bs[3][512];

    int bid = blockIdx.x;
    int wk  = (bid & 7) * 2000 + (bid >> 3);   // XCD swizzle, 16000 % 8 == 0
    int vt  = wk >> 4;                   // vocab tile 0..999 (128 rows)
    int tt  = wk & 15;                   // token tile 0..15  (128 tokens)

    const int tid  = threadIdx.x;
    const int lane = tid & 63;
    const int wv   = tid >> 6;           // wave 0..3
    const int wr   = wv >> 1;            // vocab half
    const int wc   = wv & 1;             // token half

    // wave wv stages both halves of A-frag wv and B-frag wv
    const int4* ga = wq + (size_t)(vt * 4 + wv) * 2048 + lane;
    const int4* gb = xq + (size_t)(tt * 4 + wv) * 2048 + lane;

#define STAGE(bt, t) do {                                               \
        gload16(ga + (size_t)(t) * 128,      &As[bt][(wv * 2 + 0) * 64]); \
        gload16(ga + (size_t)(t) * 128 + 64, &As[bt][(wv * 2 + 1) * 64]); \
        gload16(gb + (size_t)(t) * 128,      &Bs[bt][(wv * 2 + 0) * 64]); \
        gload16(gb + (size_t)(t) * 128 + 64, &Bs[bt][(wv * 2 + 1) * 64]); \
    } while (0)

    f32x16 acc[2][2] = {};

#define COMPUTE(bt) do {                                              \
        const int4* Ab = &As[bt][0];                                  \
        const int4* Bb = &Bs[bt][0];                                  \
        int8v a0 = ld_frag(Ab, 2 * wr + 0, lane);                     \
        int8v a1 = ld_frag(Ab, 2 * wr + 1, lane);                     \
        int8v b0 = ld_frag(Bb, 2 * wc + 0, lane);                     \
        int8v b1 = ld_frag(Bb, 2 * wc + 1, lane);                     \
        __builtin_amdgcn_s_setprio(1);                                \
        acc[0][0] = __builtin_amdgcn_mfma_scale_f32_32x32x64_f8f6f4(  \
            a0, b0, acc[0][0], 0, 0, 0, 0x7F7F7F7F, 0, 0x7F7F7F7F);   \
        acc[0][1] = __builtin_amdgcn_mfma_scale_f32_32x32x64_f8f6f4(  \
            a0, b1, acc[0][1], 0, 0, 0, 0x7F7F7F7F, 0, 0x7F7F7F7F);   \
        acc[1][0] = __builtin_amdgcn_mfma_scale_f32_32x32x64_f8f6f4(  \
            a1, b0, acc[1][0], 0, 0, 0, 0x7F7F7F7F, 0, 0x7F7F7F7F);   \
        acc[1][1] = __builtin_amdgcn_mfma_scale_f32_32x32x64_f8f6f4(  \
            a1, b1, acc[1][1], 0, 0, 0, 0x7F7F7F7F, 0, 0x7F7F7F7F);   \
        __builtin_amdgcn_s_setprio(0);                                \
    } while (0)

#define PHASE(bt_stage, ts, bt_comp) do {                             \
        asm volatile("s_waitcnt vmcnt(4)" ::: "memory");              \
        __builtin_amdgcn_s_barrier();                                 \
        asm volatile("" ::: "memory");                                \
        if ((ts) < 16) STAGE(bt_stage, ts);                           \
        COMPUTE(bt_comp);                                             \
    } while (0)

    // prologue: steps 0,1 in flight (8 outstanding loads per wave)
    STAGE(0, 0);
    STAGE(1, 1);

    for (int tb = 0; tb < 15; tb += 3) {
        PHASE(2, tb + 2, 0);             // compute step tb
        PHASE(0, tb + 3, 1);             // compute step tb+1
        PHASE(1, tb + 4, 2);             // compute step tb+2
    }
    // tail: step 15 (buf 0), all loads done
    asm volatile("s_waitcnt vmcnt(0)" ::: "memory");
    __builtin_amdgcn_s_barrier();
    asm volatile("" ::: "memory");
    COMPUTE(0);

#undef PHASE
#undef COMPUTE
#undef STAGE

    // epilogue: softcap+exp, reduce over this wave's 64 vocab rows, atomics per token
    #pragma unroll
    for (int j = 0; j < 2; ++j) {
        float e = 0.f;
        #pragma unroll
        for (int m = 0; m < 2; ++m) {
            #pragma unroll
            for (int r = 0; r < 16; ++r) e += expterm(acc[m][j][r]);
        }
        e += __shfl_xor(e, 32, 64);      // lanes l, l+32: same token col, other row half
        if (lane < 32) {
            atomicAdd(&rowsum[tt * 128 + (wc * 2 + j) * 32 + lane], e);
        }
    }
}

// ---------------- fallback GEMM (bf16, W f32 reg-staged) — used if ws too small ----------------
__global__ __launch_bounds__(256, 3) void gemm_sumexp_fb(const float* __restrict__ W,
                                                         const short8* __restrict__ xf,
                                                         float* __restrict__ rowsum) {
    __shared__ short8 As[2][512];
    __shared__ short8 Bs[2][512];
    int bid = blockIdx.x;
    int wk  = (bid & 7) * 2000 + (bid >> 3);
    int vt  = wk >> 4;
    int tt  = wk & 15;
    const int tid  = threadIdx.x;
    const int lane = tid & 63;
    const int wid  = tid >> 6;
    const int wr   = (wid >> 1) & 1;
    const int wc   = wid & 1;
    const int mt_s = tid >> 5;
    const int sl   = tid & 31;
    const float* arow_p = W + (size_t)(vt * 128 + mt_s * 16 + (sl & 15)) * K_DIM + ((sl >> 4) << 3);
    const int nt0 = wid << 1;
    const char* gb_base = (const char*)xf + ((((size_t)(tt * 8 + nt0)) * KT_N) * 64 + lane) * 16;
    {
        const float4* gaq = (const float4*)(arow_p + 0);
        float4 p0 = gaq[0], p1 = gaq[1], p2 = gaq[4], p3 = gaq[5];
        gload16(gb_base,         &Bs[0][nt0 * 64]);
        gload16(gb_base + 32768, &Bs[0][(nt0 + 1) * 64]);
        As[0][mt_s * 64 + sl]      = pack8(p0, p1);
        As[0][mt_s * 64 + sl + 32] = pack8(p2, p3);
    }
    __syncthreads();
    f32x4 acc[4][4] = {};
    int cur = 0;
    for (int t = 0; t < 32; ++t) {
        float4 q0, q1, q2, q3;
        if (t + 1 < 32) {
            const float4* gaq = (const float4*)(arow_p + (t + 1) * 32);
            q0 = gaq[0]; q1 = gaq[1]; q2 = gaq[4]; q3 = gaq[5];
            gload16(gb_base + (size_t)(t + 1) * 1024,         &Bs[cur ^ 1][nt0 * 64]);
            gload16(gb_base + (size_t)(t + 1) * 1024 + 32768, &Bs[cur ^ 1][(nt0 + 1) * 64]);
        }
        short8 af0 = As[cur][(wr * 4 + 0) * 64 + lane];
        short8 af1 = As[cur][(wr * 4 + 1) * 64 + lane];
        short8 af2 = As[cur][(wr * 4 + 2) * 64 + lane];
        short8 af3 = As[cur][(wr * 4 + 3) * 64 + lane];
        short8 bf0 = Bs[cur][(wc * 4 + 0) * 64 + lane];
        short8 bf1 = Bs[cur][(wc * 4 + 1) * 64 + lane];
        short8 bf2 = Bs[cur][(wc * 4 + 2) * 64 + lane];
        short8 bf3 = Bs[cur][(wc * 4 + 3) * 64 + lane];
        acc[0][0] = __builtin_amdgcn_mfma_f32_16x16x32_bf16(af0, bf0, acc[0][0], 0, 0, 0);
        acc[0][1] = __builtin_amdgcn_mfma_f32_16x16x32_bf16(af0, bf1, acc[0][1], 0, 0, 0);
        acc[0][2] = __builtin_amdgcn_mfma_f32_16x16x32_bf16(af0, bf2, acc[0][2], 0, 0, 0);
        acc[0][3] = __builtin_amdgcn_mfma_f32_16x16x32_bf16(af0, bf3, acc[0][3], 0, 0, 0);
        acc[1][0] = __builtin_amdgcn_mfma_f32_16x16x32_bf16(af1, bf0, acc[1][0], 0, 0, 0);
        acc[1][1] = __builtin_amdgcn_mfma_f32_16x16x32_bf16(af1, bf1, acc[1][1], 0, 0, 0);
        acc[1][2] = __builtin_amdgcn_mfma_f32_16x16x32_bf16(af1, bf2, acc[1][2], 0, 0, 0);
        acc[1][3] = __builtin_amdgcn_mfma_f32_16x16x32_bf16(af1, bf3, acc[1][3], 0, 0, 0);
        acc[2][0] = __builtin_amdgcn_mfma_f32_16x16x32_bf16(af2, bf0, acc[2][0], 0, 0, 0);
        acc[2][1] = __builtin_amdgcn_mfma_f32_16x16x32_bf16(af2, bf1, acc[2][1], 0, 0, 0);
        acc[2][2] = __builtin_amdgcn_mfma_f32_16x16x32_bf16(af2, bf2, acc[2][2], 0, 0, 0);
        acc[2][3] = __builtin_amdgcn_mfma_f32_16x16x32_bf16(af2, bf3, acc[2][3], 0, 0, 0);
        acc[3][0] = __builtin_amdgcn_mfma_f32_16x16x32_bf16(af3, bf0, acc[3][0], 0, 0, 0);
        acc[3][1] = __builtin_amdgcn_mfma_f32_16x16x32_bf16(af3, bf1, acc[3][1], 0, 0, 0);
        acc[3][2] = __builtin_amdgcn_mfma_f32_16x16x32_bf16(af3, bf2, acc[3][2], 0, 0, 0);
        acc[3][3] = __builtin_amdgcn_mfma_f32_16x16x32_bf16(af3, bf3, acc[3][3], 0, 0, 0);
        if (t + 1 < 32) {
            As[cur ^ 1][mt_s * 64 + sl]      = pack8(q0, q1);
            As[cur ^ 1][mt_s * 64 + sl + 32] = pack8(q2, q3);
        }
        __syncthreads();
        cur ^= 1;
    }
    float s0 = 0.f, s1 = 0.f, s2 = 0.f, s3 = 0.f;
    #pragma unroll
    for (int mi = 0; mi < 4; ++mi) {
        #pragma unroll
        for (int r = 0; r < 4; ++r) {
            float l0 = acc[mi][0][r], l1 = acc[mi][1][r];
            float l2 = acc[mi][2][r], l3 = acc[mi][3][r];
            s0 += exp2f(CAP_C2 * __builtin_amdgcn_rcpf(exp2f(l0 * CAP_C1) + 1.0f));
            s1 += exp2f(CAP_C2 * __builtin_amdgcn_rcpf(exp2f(l1 * CAP_C1) + 1.0f));
            s2 += exp2f(CAP_C2 * __builtin_amdgcn_rcpf(exp2f(l2 * CAP_C1) + 1.0f));
            s3 += exp2f(CAP_C2 * __builtin_amdgcn_rcpf(exp2f(l3 * CAP_C1) + 1.0f));
        }
    }
    s0 += __shfl_xor(s0, 16, 64); s0 += __shfl_xor(s0, 32, 64);
    s1 += __shfl_xor(s1, 16, 64); s1 += __shfl_xor(s1, 32, 64);
    s2 += __shfl_xor(s2, 16, 64); s2 += __shfl_xor(s2, 32, 64);
    s3 += __shfl_xor(s3, 16, 64); s3 += __shfl_xor(s3, 32, 64);
    if (lane < 16) {
        int tbase = tt * 128 + wc * 64 + lane;
        atomicAdd(&rowsum[tbase +  0], s0);
        atomicAdd(&rowsum[tbase + 16], s1);
        atomicAdd(&rowsum[tbase + 32], s2);
        atomicAdd(&rowsum[tbase + 48], s3);
    }
}

// ---------------- exact-f32 label logits ----------------
__global__ __launch_bounds__(256) void label_kernel(const float* __restrict__ x,
                                                    const float* __restrict__ W,
                                                    const int* __restrict__ target,
                                                    float* __restrict__ slabel) {
    int t    = blockIdx.x * 4 + (threadIdx.x >> 6);
    int lane = threadIdx.x & 63;
    int tg   = target[t];
    int lbl  = (tg == -100) ? 0 : tg;
    const float4* xr = (const float4*)(x + (size_t)t * K_DIM);
    const float4* wv = (const float4*)(W + (size_t)lbl * K_DIM);
    float sum = 0.0f;
    #pragma unroll
    for (int i = 0; i < 4; ++i) {
        float4 a = xr[lane + i * 64];
        float4 b = wv[lane + i * 64];
        sum += a.x * b.x + a.y * b.y + a.z * b.z + a.w * b.w;
    }
    #pragma unroll
    for (int off = 1; off < 64; off <<= 1) sum += __shfl_xor(sum, off, 64);
    if (lane == 0) {
        float t0 = exp2f(sum * CAP_C1);
        slabel[t] = 30.0f - 60.0f / (t0 + 1.0f);
    }
}

// ---------------- finalize ----------------
__global__ __launch_bounds__(256) void finalize_kernel(const float* __restrict__ rowsum,
                                                       const float* __restrict__ slabel,
                                                       const int* __restrict__ target,
                                                       float* __restrict__ out) {
    __shared__ double ssum[4];
    __shared__ int    scnt[4];
    int w    = threadIdx.x >> 6;
    int lane = threadIdx.x & 63;
    double acc = 0.0;
    int cnt = 0;
    #pragma unroll
    for (int j = 0; j < 8; ++j) {
        int t = w * 512 + j * 64 + lane;
        int tg = target[t];
        if (tg != -100) {
            float lse = 30.0f + logf(rowsum[t]);
            acc += (double)(slabel[t] - lse);
            cnt += 1;
        }
    }
    #pragma unroll
    for (int off = 1; off < 64; off <<= 1) {
        acc += __shfl_xor(acc, off, 64);
        cnt += __shfl_xor(cnt, off, 64);
    }
    if (lane == 0) { ssum[w] = acc; scnt[w] = cnt; }
    __syncthreads();
    if (threadIdx.x == 0) {
        double c0 = ssum[0] / (double)scnt[0];
        double c1 = ssum[1] / (double)scnt[1];
        double r0 = ssum[2] / (double)scnt[2];
        double r1 = ssum[3] / (double)scnt[3];
        out[0] = (float)(-0.1 * 0.5 * ((c0 - r0) + (c1 - r1)));
    }
}

extern "C" void kernel_launch(void* const* d_in, const int* in_sizes, int n_in,
                              void* d_out, int out_size, void* d_ws, size_t ws_size,
                              hipStream_t stream) {
    const float* x      = (const float*)d_in[0];
    const float* W      = (const float*)d_in[1];
    const int*   target = (const int*)d_in[2];
    float*       out    = (float*)d_out;

    char*   ws     = (char*)d_ws;
    float*  rowsum = (float*)(ws + WS_ROWSUM);
    float*  slabel = (float*)(ws + WS_SLABEL);

    hipMemsetAsync(rowsum, 0, M_TOK * sizeof(float), stream);

    if (ws_size >= WS_REQ) {
        int4* xq = (int4*)(ws + WS_XQ);
        int4* wq = (int4*)(ws + WS_WQ);
        convert_fp8_kernel<<<256, 256, 0, stream>>>(x, xq, 1.0f);
        convert_fp8_kernel<<<16000, 256, 0, stream>>>(W, wq, 32.0f);
        gemm_sumexp_fp8_ring<<<16000, 256, 0, stream>>>(wq, xq, rowsum);
    } else {
        short8* xf = (short8*)(ws + WS_XFB);
        convert_x_kernel<<<M_TOK * (K_DIM / 8) / 256, 256, 0, stream>>>(x, xf);
        gemm_sumexp_fb<<<16000, 256, 0, stream>>>(W, xf, rowsum);
    }

    label_kernel<<<M_TOK / 4, 256, 0, stream>>>(x, W, target, slabel);
    finalize_kernel<<<1, 256, 0, stream>>>(rowsum, slabel, target, out);
}